// Round 7
// baseline (1022.482 us; speedup 1.0000x reference)
//
#include <hip/hip_runtime.h>
#include <hip/hip_cooperative_groups.h>

namespace cg = cooperative_groups;

#define BATCH   8
#define NNODE   2048
#define CH      256
#define NEDGE   32768
#define NLAYER  3
#define MROWS   (NNODE*BATCH)      // 16384 rows (n-major: row = n*8 + b)
#define KCAT    (3*CH)             // 768
#define NTOT    (MROWS*CH)         // 4,194,304 elements of h

typedef _Float16 half8 __attribute__((ext_vector_type(8)));
typedef _Float16 half4 __attribute__((ext_vector_type(4)));
typedef float    f32x4 __attribute__((ext_vector_type(4)));

// ---------------- workspace layout (bytes) ----------------
// Acat cols: [0:256)=X raw h f16, [256:512)=P1=prop(X), [512:768)=P2=prop(P1)
#define OFF_H      ((size_t)0)            // fp32 h [MROWS][CH]       16,777,216
#define OFF_ACAT   ((size_t)16777216)     // f16 [MROWS][768]         25,165,824
#define OFF_HF     ((size_t)41943040)     // f16 Hf [MROWS][256]       8,388,608
#define OFF_WT     ((size_t)50331648)     // f16 Wt [3][CH][KCAT]      1,179,648
#define OFF_MT     ((size_t)51511296)     // f16 Mt [3][CH][CH]          393,216
#define OFF_PARTA  ((size_t)51904512)     // float2[1024]                  8,192
#define OFF_PARTB  ((size_t)51912704)     // float2[1024]                  8,192
#define OFF_CS     ((size_t)51920896)     // f32 cs[3][3][256]             9,216
#define OFF_CSM    ((size_t)51930112)     // f32 csM[3][256]               3,072
#define OFF_DEG    ((size_t)51933184)     // f32 deg[3][NNODE]            24,576
#define OFF_CNT    ((size_t)51957760)     // u32 count[3][NNODE]          24,576
#define OFF_ELIST  ((size_t)51982336)     // u32 elist[3][NNODE][64]   1,572,864
#define OFF_NORM   ((size_t)53555200)     // f32 norm[3][NEDGE]          393,216
#define OFF_R1     ((size_t)53948416)     // f32 r1[3][NNODE]             24,576
#define OFF_R2     ((size_t)53972992)     // f32 r2[3][NNODE]             24,576
#define OFF_MP     ((size_t)53997568)     // f32 meanpart[8][64][CH]     524,288

#define SMEM_BYTES 18448   // gemm: Als 8192 | Bls 8192 | red 2048 | mv 8

__device__ __forceinline__ void async_lds16(const void* g, void* l) {
  __builtin_amdgcn_global_load_lds((const __attribute__((address_space(1))) void*)g,
                                   (__attribute__((address_space(3))) void*)l, 16, 0, 0);
}

// ---- weight fold+transpose, one 64x64 tile (tile < 192) ----
__device__ __forceinline__ void weights_tile(int tile, int t,
                                             const float* __restrict__ cheb_w,
                                             const float* __restrict__ mlp_w,
                                             _Float16* __restrict__ Wt,
                                             _Float16* __restrict__ Mt,
                                             char* smem) {
  _Float16 (*lt)[72] = (_Float16(*)[72])smem;
  const int rr = t >> 4, c4 = t & 15;
  if (tile < 144) {
    const int l = tile / 48, rem = tile % 48;
    const int kk = rem / 16, q = rem % 16, ci = q >> 2, ni = q & 3;
    const float4* W  = (const float4*)cheb_w + ((size_t)((l*3 + kk)*CH + ci*64))*64 + ni*16;
    const float4* W2 = (const float4*)cheb_w + ((size_t)((l*3 + 2 )*CH + ci*64))*64 + ni*16;
    #pragma unroll
    for (int p = 0; p < 4; ++p) {
      const int r = p*16 + rr;
      float4 v = W[(size_t)r*64 + c4];
      if (kk == 0) {
        float4 v2 = W2[(size_t)r*64 + c4];
        v.x -= v2.x; v.y -= v2.y; v.z -= v2.z; v.w -= v2.w;
      } else if (kk == 2) {
        v.x *= 2.f; v.y *= 2.f; v.z *= 2.f; v.w *= 2.f;
      }
      lt[c4*4+0][r] = (_Float16)v.x; lt[c4*4+1][r] = (_Float16)v.y;
      lt[c4*4+2][r] = (_Float16)v.z; lt[c4*4+3][r] = (_Float16)v.w;
    }
    __syncthreads();
    const int nr = t >> 2, ch2 = t & 3;
    #pragma unroll
    for (int pp = 0; pp < 2; ++pp) {
      const int ch = ch2 + pp*4;
      half8 v = *(const half8*)&lt[nr][ch*8];
      *(half8*)&Wt[((size_t)(l*CH + ni*64 + nr))*KCAT + kk*256 + ci*64 + ch*8] = v;
    }
  } else {
    const int m = tile - 144;
    const int l = m / 16, q = m % 16, ci = q >> 2, ni = q & 3;
    const float4* W = (const float4*)mlp_w + ((size_t)(l*CH + ci*64))*64 + ni*16;
    #pragma unroll
    for (int p = 0; p < 4; ++p) {
      const int r = p*16 + rr;
      float4 v = W[(size_t)r*64 + c4];
      lt[c4*4+0][r] = (_Float16)v.x; lt[c4*4+1][r] = (_Float16)v.y;
      lt[c4*4+2][r] = (_Float16)v.z; lt[c4*4+3][r] = (_Float16)v.w;
    }
    __syncthreads();
    const int nr = t >> 2, ch2 = t & 3;
    #pragma unroll
    for (int pp = 0; pp < 2; ++pp) {
      const int ch = ch2 + pp*4;
      half8 v = *(const half8*)&lt[nr][ch*8];
      *(half8*)&Mt[((size_t)(l*CH + ni*64 + nr))*CH + ci*64 + ch*8] = v;
    }
  }
}

// ---- sparse prop: one wave per (dst, 4 batches), grid-stride over 4096 wave-jobs ----
__device__ __forceinline__ void prop_phase(_Float16* __restrict__ Acat,
                                           int src_off, int dst_off,
                                           const int* __restrict__ rows,
                                           const float* __restrict__ nrm,
                                           const unsigned int* __restrict__ count,
                                           const unsigned int* __restrict__ el) {
  const int w = threadIdx.x >> 6, lane = threadIdx.x & 63;
  const int stride = gridDim.x*4;
  for (int g = blockIdx.x*4 + w; g < 4096; g += stride) {
    const int dst = g >> 1, bb = (g & 1) << 2;     // 4 batches per wave
    unsigned int c = count[dst]; if (c > 64u) c = 64u;
    int srcv = 0; float nmv = 0.f;
    if (lane < (int)c) {
      unsigned int e = el[(size_t)dst*64 + lane];
      srcv = rows[e]; nmv = nrm[e];
    }
    float acc[4][4] = {{0.f,0.f,0.f,0.f},{0.f,0.f,0.f,0.f},{0.f,0.f,0.f,0.f},{0.f,0.f,0.f,0.f}};
    const _Float16* base = Acat + src_off + lane*4;
    for (unsigned int i = 0; i < c; ++i) {
      int   src = __builtin_amdgcn_readlane(srcv, i);
      int   nbi = __builtin_amdgcn_readlane(__builtin_bit_cast(int, nmv), i);
      float nm  = __builtin_bit_cast(float, nbi);
      const _Float16* p = base + (size_t)(src*8 + bb)*KCAT;
      #pragma unroll
      for (int j = 0; j < 4; ++j) {
        half4 v = *(const half4*)(p + (size_t)j*KCAT);
        acc[j][0] += nm*(float)v[0]; acc[j][1] += nm*(float)v[1];
        acc[j][2] += nm*(float)v[2]; acc[j][3] += nm*(float)v[3];
      }
    }
    #pragma unroll
    for (int j = 0; j < 4; ++j) {
      half4 o; o[0]=(_Float16)acc[j][0]; o[1]=(_Float16)acc[j][1];
      o[2]=(_Float16)acc[j][2]; o[3]=(_Float16)acc[j][3];
      *(half4*)&Acat[(size_t)(dst*8 + bb + j)*KCAT + dst_off + lane*4] = o;
    }
  }
}

// ---- MFMA GEMM: grid-stride over 1024 64x64 tiles, LN folded into epilogue ----
template<int KSTEPS, int DO_GELU>
__device__ __forceinline__ void gemm_phase(const _Float16* __restrict__ A, int lda,
                                           const _Float16* __restrict__ Bt, int ldb,
                                           const float* __restrict__ bias,
                                           const float* __restrict__ csv,
                                           const float* __restrict__ r1v,
                                           const float* __restrict__ r2v,
                                           const float2* __restrict__ part_in,
                                           float2* __restrict__ part_out,
                                           float* __restrict__ H,
                                           _Float16* __restrict__ Of, int ofs,
                                           char* smem) {
  _Float16* Als = (_Float16*)smem;
  _Float16* Bls = (_Float16*)(smem + 8192);
  float* red = (float*)(smem + 16384);
  float* mv  = (float*)(smem + 18432);
  const int NB = gridDim.x;
  const int t = threadIdx.x;
  const int w = t >> 6, lane = t & 63;
  const int quad = lane >> 4, l16 = lane & 15;
  const int wm = w & 1, wn = w >> 1;

  // reduce stats partials of input h -> (mean, istd)
  {
    float s = 0.f, s2 = 0.f;
    for (int i = t; i < NB; i += 256) { float2 p = part_in[i]; s += p.x; s2 += p.y; }
    red[t] = s; red[256+t] = s2; __syncthreads();
    for (int o = 128; o > 0; o >>= 1) {
      if (t < o) { red[t] += red[t+o]; red[256+t] += red[256+t+o]; }
      __syncthreads();
    }
    if (t == 0) {
      float mean = red[0] * (1.f/(float)NTOT);
      float var  = red[256] * (1.f/(float)NTOT) - mean*mean;
      mv[0] = mean; mv[1] = rsqrtf(var + 1e-5f);
    }
    __syncthreads();
  }
  const float mean = mv[0], istd = mv[1];
  const float mi = -mean * istd;

  const int c0 = w*64 + lane, c1 = 256 + w*64 + lane;
  const int r0 = c0 >> 3, s0 = (c0 & 7) ^ (r0 & 7);
  const int r1i = c1 >> 3, s1 = (c1 & 7) ^ (r1i & 7);
  _Float16* lA0 = &Als[w*512];
  _Float16* lA1 = &Als[2048 + w*512];
  _Float16* lB0 = &Bls[w*512];
  _Float16* lB1 = &Bls[2048 + w*512];
  const int ra0 = wm*32 + l16, ra1 = ra0 + 16;
  const int rb0 = wn*32 + l16, rb1 = rb0 + 16;

  float s = 0.f, s2 = 0.f;
  for (int vt = blockIdx.x; vt < 1024; vt += NB) {
    const int bm = vt & 255, bn = vt >> 8;
    f32x4 acc00 = {0.f,0.f,0.f,0.f};
    f32x4 acc01 = acc00, acc10 = acc00, acc11 = acc00;
    const _Float16* ga0 = A  + (size_t)(bm*64 + r0)*lda + s0*8;
    const _Float16* ga1 = A  + (size_t)(bm*64 + r1i)*lda + s1*8;
    const _Float16* gb0 = Bt + (size_t)(bn*64 + r0)*ldb + s0*8;
    const _Float16* gb1 = Bt + (size_t)(bn*64 + r1i)*ldb + s1*8;
    __syncthreads();   // protect Als/Bls reuse across virtual tiles
    for (int ks = 0; ks < KSTEPS; ++ks) {
      async_lds16(ga0, lA0); async_lds16(ga1, lA1);
      async_lds16(gb0, lB0); async_lds16(gb1, lB1);
      ga0 += 64; ga1 += 64; gb0 += 64; gb1 += 64;
      __syncthreads();
      #pragma unroll
      for (int kh = 0; kh < 2; ++kh) {
        const int q = kh*4 + quad;
        half8 a0 = *(const half8*)&Als[ra0*64 + (q ^ (ra0 & 7))*8];
        half8 a1 = *(const half8*)&Als[ra1*64 + (q ^ (ra1 & 7))*8];
        half8 b0 = *(const half8*)&Bls[rb0*64 + (q ^ (rb0 & 7))*8];
        half8 b1 = *(const half8*)&Bls[rb1*64 + (q ^ (rb1 & 7))*8];
        acc00 = __builtin_amdgcn_mfma_f32_16x16x32_f16(a0, b0, acc00, 0, 0, 0);
        acc01 = __builtin_amdgcn_mfma_f32_16x16x32_f16(a0, b1, acc01, 0, 0, 0);
        acc10 = __builtin_amdgcn_mfma_f32_16x16x32_f16(a1, b0, acc10, 0, 0, 0);
        acc11 = __builtin_amdgcn_mfma_f32_16x16x32_f16(a1, b1, acc11, 0, 0, 0);
      }
      __syncthreads();
    }

    const int gm0 = bm*64 + wm*32, gn0 = bn*64 + wn*32;
    #pragma unroll
    for (int i = 0; i < 2; ++i) {
      #pragma unroll
      for (int j = 0; j < 2; ++j) {
        f32x4 a = (i == 0) ? (j == 0 ? acc00 : acc01) : (j == 0 ? acc10 : acc11);
        const int col = gn0 + j*16 + l16;
        const float bv = bias[col];
        const float c0v = csv[col];
        float c1v = 0.f, c2v = 0.f;
        if (!DO_GELU) { c1v = csv[256 + col]; c2v = csv[512 + col]; }
        #pragma unroll
        for (int r = 0; r < 4; ++r) {
          const int row = gm0 + i*16 + quad*4 + r;  // C/D: col=lane&15, row=quad*4+reg
          float v;
          if (DO_GELU) {
            v = istd*a[r] + mi*c0v + bv;
            v = 0.5f*v*(1.f + erff(v*0.70710678118654752f));
          } else {
            const int node = row >> 3;
            v = istd*a[r] + mi*(c0v + r1v[node]*c1v + r2v[node]*c2v) + bv;
          }
          float hv = H[(size_t)row*CH + col] + v;
          H[(size_t)row*CH + col] = hv;
          Of[(size_t)row*ofs + col] = (_Float16)hv;
          s += hv; s2 += hv*hv;
        }
      }
    }
  }
  __syncthreads();
  red[t] = s; red[256+t] = s2; __syncthreads();
  for (int o = 128; o > 0; o >>= 1) {
    if (t < o) { red[t] += red[t+o]; red[256+t] += red[256+t+o]; }
    __syncthreads();
  }
  if (t == 0) part_out[blockIdx.x] = make_float2(red[0], red[256]);
  __syncthreads();
}

// ================= the whole pipeline in ONE cooperative kernel =================
extern "C" __global__ __launch_bounds__(256, 2)
void k_mega(const float* __restrict__ x, const float* __restrict__ ew,
            const float* __restrict__ cheb_w, const float* __restrict__ cheb_b,
            const float* __restrict__ mlp_w, const float* __restrict__ mlp_b,
            const int* __restrict__ ei, float* __restrict__ out,
            float* __restrict__ h, _Float16* __restrict__ Acat,
            _Float16* __restrict__ Hf, _Float16* __restrict__ Wt,
            _Float16* __restrict__ Mt, float2* __restrict__ partA,
            float2* __restrict__ partB, float* __restrict__ cs,
            float* __restrict__ csM, float* __restrict__ deg,
            unsigned int* __restrict__ cntp, unsigned int* __restrict__ elist,
            float* __restrict__ norm, float* __restrict__ r1,
            float* __restrict__ r2, float* __restrict__ mp) {
  cg::grid_group grid = cg::this_grid();
  __shared__ __align__(16) char smem[SMEM_BYTES];
  const int blk = blockIdx.x, t = threadIdx.x;
  const int NB = gridDim.x;
  const int tid = blk*256 + t;
  const int nthreads = NB*256;

  // ---- ph0: transpose + f16 copy + LN0 stats | zero | weight tiles ----
  {
    float* rs = (float*)smem;
    float s = 0.f, s2 = 0.f;
    for (int i = tid; i < NTOT/4; i += nthreads) {
      int c4 = i & 63, b = (i >> 6) & 7, n = i >> 9;
      float4 v = ((const float4*)x)[((b*NNODE + n) << 6) + c4];
      ((float4*)h)[i] = v;
      half4 o; o[0]=(_Float16)v.x; o[1]=(_Float16)v.y; o[2]=(_Float16)v.z; o[3]=(_Float16)v.w;
      *(half4*)&Acat[(size_t)(i >> 6)*KCAT + c4*4] = o;
      s  += v.x + v.y + v.z + v.w;
      s2 += v.x*v.x + v.y*v.y + v.z*v.z + v.w*v.w;
    }
    rs[t] = s; rs[256+t] = s2; __syncthreads();
    for (int o = 128; o > 0; o >>= 1) {
      if (t < o) { rs[t] += rs[t+o]; rs[256+t] += rs[256+t+o]; }
      __syncthreads();
    }
    if (t == 0) partA[blk] = make_float2(rs[0], rs[256]);
    for (int i = tid; i < NLAYER*NNODE; i += nthreads) { deg[i] = 0.f; cntp[i] = 0u; r1[i] = 0.f; }
    for (int tile = blk; tile < 192; tile += NB) {
      __syncthreads();
      weights_tile(tile, t, cheb_w, mlp_w, Wt, Mt, smem);
    }
  }
  grid.sync();

  // ---- ph1: edge scatter (deg, count, elist) ----
  for (int i = tid; i < NLAYER*NEDGE; i += nthreads) {
    int l = i / NEDGE, e = i % NEDGE;
    const int* rows = ei + l*2*NEDGE;
    const int* cols = rows + NEDGE;
    int r = rows[e], c = cols[e];
    float wv = (r == c) ? 0.f : ew[i];
    atomicAdd(&deg[l*NNODE + r], wv);
    unsigned int slot = atomicAdd(&cntp[l*NNODE + c], 1u);
    if (slot < 64u) elist[(size_t)(l*NNODE + c)*64 + slot] = (unsigned int)e;
  }
  grid.sync();

  // ---- ph2: edge norm + r1 accumulation ----
  for (int i = tid; i < NLAYER*NEDGE; i += nthreads) {
    int l = i / NEDGE, e = i % NEDGE;
    const int* rows = ei + l*2*NEDGE;
    const int* cols = rows + NEDGE;
    int r = rows[e], c = cols[e];
    float wv = (r == c) ? 0.f : ew[i];
    float dr = deg[l*NNODE + r], dc = deg[l*NNODE + c];
    float ir = dr > 0.f ? rsqrtf(fmaxf(dr, 1e-12f)) : 0.f;
    float ic = dc > 0.f ? rsqrtf(fmaxf(dc, 1e-12f)) : 0.f;
    float nm = -(ir * wv * ic);
    norm[i] = nm;
    atomicAdd(&r1[l*NNODE + c], nm);
  }
  grid.sync();

  // ---- ph3: r2 = prop(r1) | colsums cs/csM from f16 weights ----
  for (int i = tid; i < 9216; i += nthreads) {
    if (i < NLAYER*NNODE) {
      int l = i / NNODE;
      const int* rows = ei + l*2*NEDGE;
      unsigned int c = cntp[i]; if (c > 64u) c = 64u;
      const unsigned int* el = elist + (size_t)i*64;
      float s = 0.f;
      for (unsigned int j = 0; j < c; ++j) {
        unsigned int e = el[j];
        s += norm[l*NEDGE + e] * r1[l*NNODE + rows[e]];
      }
      r2[i] = s;
    } else if (i < 8448) {
      int j = i - 6144, idx = j >> 8, n = j & 255;
      int l = idx / 3, kk = idx % 3;
      const half8* row = (const half8*)&Wt[((size_t)(l*CH + n))*KCAT + kk*256];
      float s = 0.f;
      #pragma unroll 4
      for (int k = 0; k < 32; ++k) {
        half8 v = row[k];
        s += (float)v[0]+(float)v[1]+(float)v[2]+(float)v[3]
           + (float)v[4]+(float)v[5]+(float)v[6]+(float)v[7];
      }
      cs[idx*CH + n] = s;
    } else {
      int j = i - 8448, l = j >> 8, n = j & 255;
      const half8* row = (const half8*)&Mt[((size_t)(l*CH + n))*CH];
      float s = 0.f;
      #pragma unroll 4
      for (int k = 0; k < 32; ++k) {
        half8 v = row[k];
        s += (float)v[0]+(float)v[1]+(float)v[2]+(float)v[3]
           + (float)v[4]+(float)v[5]+(float)v[6]+(float)v[7];
      }
      csM[l*CH + n] = s;
    }
  }
  grid.sync();

  // ---- layers ----
  for (int l = 0; l < NLAYER; ++l) {
    const int* rows_l = ei + l*2*NEDGE;
    const unsigned int* cnt_l = cntp + l*NNODE;
    const unsigned int* el_l  = elist + (size_t)l*NNODE*64;
    const float* norm_l = norm + l*NEDGE;

    prop_phase(Acat, 0, 256, rows_l, norm_l, cnt_l, el_l);
    grid.sync();
    prop_phase(Acat, 256, 512, rows_l, norm_l, cnt_l, el_l);
    grid.sync();
    gemm_phase<12, 0>(Acat, KCAT, Wt + (size_t)l*CH*KCAT, KCAT,
                      cheb_b + l*CH, cs + l*3*CH, r1 + l*NNODE, r2 + l*NNODE,
                      partA, partB, h, Hf, CH, smem);
    grid.sync();
    gemm_phase<4, 1>(Hf, CH, Mt + (size_t)l*CH*CH, CH,
                     mlp_b + l*CH, csM + l*CH, r1, r2,
                     partB, partA, h, Acat, KCAT, smem);
    grid.sync();
  }

  // ---- final mean over N ----
  for (int v = blk; v < 512; v += NB) {
    int b = v & 7, chunk = v >> 3;
    float s = 0.f;
    for (int k = 0; k < 32; ++k) {
      int n = chunk*32 + k;
      s += h[((size_t)(n*8 + b) << 8) + t];
    }
    mp[((b*64 + chunk) << 8) + t] = s;
  }
  grid.sync();
  if (blk < 8) {
    float s = 0.f;
    for (int ch = 0; ch < 64; ++ch) s += mp[((blk*64 + ch) << 8) + t];
    out[(blk << 8) + t] = s * (1.f/(float)NNODE);
  }
}

extern "C" void kernel_launch(void* const* d_in, const int* in_sizes, int n_in,
                              void* d_out, int out_size, void* d_ws, size_t ws_size,
                              hipStream_t stream) {
  const float* x      = (const float*)d_in[0];   // node_feature [8,2048,256]
  const float* ew     = (const float*)d_in[1];   // edge_weight [3,32768]
  const float* cheb_w = (const float*)d_in[2];   // [3,3,256,256]
  const float* cheb_b = (const float*)d_in[3];   // [3,256]
  const float* mlp_w  = (const float*)d_in[4];   // [3,256,256]
  const float* mlp_b  = (const float*)d_in[5];   // [3,256]
  const int*   ei     = (const int*)d_in[6];     // [3,2,32768]
  float* out = (float*)d_out;

  char* ws = (char*)d_ws;
  float*        h     = (float*)(ws + OFF_H);
  _Float16*     Acat  = (_Float16*)(ws + OFF_ACAT);
  _Float16*     Hf    = (_Float16*)(ws + OFF_HF);
  _Float16*     Wt    = (_Float16*)(ws + OFF_WT);
  _Float16*     Mt    = (_Float16*)(ws + OFF_MT);
  float2*       partA = (float2*)(ws + OFF_PARTA);
  float2*       partB = (float2*)(ws + OFF_PARTB);
  float*        cs    = (float*)(ws + OFF_CS);
  float*        csM   = (float*)(ws + OFF_CSM);
  float*        deg   = (float*)(ws + OFF_DEG);
  unsigned int* cntp  = (unsigned int*)(ws + OFF_CNT);
  unsigned int* elist = (unsigned int*)(ws + OFF_ELIST);
  float*        norm  = (float*)(ws + OFF_NORM);
  float*        r1    = (float*)(ws + OFF_R1);
  float*        r2    = (float*)(ws + OFF_R2);
  float*        mp    = (float*)(ws + OFF_MP);

  // grid = max co-resident blocks (capped at 1024); kernel is grid-size-agnostic
  int nb = 0;
  if (hipOccupancyMaxActiveBlocksPerMultiprocessor(&nb, (const void*)k_mega, 256, 0)
        != hipSuccess || nb < 1) nb = 2;
  int grid = nb * 256;
  if (grid > 1024) grid = 1024;

  void* args[] = { &x, &ew, &cheb_w, &cheb_b, &mlp_w, &mlp_b, &ei, &out,
                   &h, &Acat, &Hf, &Wt, &Mt, &partA, &partB, &cs, &csM,
                   &deg, &cntp, &elist, &norm, &r1, &r2, &mp };
  hipLaunchCooperativeKernel((void*)k_mega, dim3(grid), dim3(256), args, 0, stream);
}

// Round 8
// 314.992 us; speedup vs baseline: 3.2461x; 3.2461x over previous
//
#include <hip/hip_runtime.h>

#define BATCH   8
#define NNODE   2048
#define CH      256
#define NEDGE   32768
#define NLAYER  3
#define MROWS   (NNODE*BATCH)      // 16384 rows (n-major: row = n*8 + b)
#define KCAT    (3*CH)             // 768
#define NTOT    (MROWS*CH)         // 4,194,304 elements of h

typedef _Float16 half8 __attribute__((ext_vector_type(8)));
typedef _Float16 half4 __attribute__((ext_vector_type(4)));
typedef float    f32x4 __attribute__((ext_vector_type(4)));

// ---------------- workspace layout (bytes) ----------------
// h lives ONLY in f16: Acat[:,0:256) is the current h; Hf is the mid-layer h.
// Acat cols: [0:256)=h f16, [256:512)=P1=prop(h), [512:768)=P2=prop(P1)
#define OFF_ACAT   ((size_t)0)            // f16 [MROWS][768]         25,165,824
#define OFF_HF     ((size_t)25165824)     // f16 Hf [MROWS][256]       8,388,608
#define OFF_WT     ((size_t)33554432)     // f16 Wt [3][CH][KCAT]      1,179,648
#define OFF_MT     ((size_t)34734080)     // f16 Mt [3][CH][CH]          393,216
#define OFF_PARTA  ((size_t)35127296)     // float2[1024]                  8,192
#define OFF_PARTB  ((size_t)35135488)     // float2[1024]                  8,192
#define OFF_CS     ((size_t)35143680)     // f32 cs[3][3][256]             9,216
#define OFF_CSM    ((size_t)35152896)     // f32 csM[3][256]               3,072
#define OFF_DEG    ((size_t)35155968)     // f32 deg[3][NNODE]            24,576
#define OFF_CNT    ((size_t)35180544)     // u32 count[3][NNODE]          24,576
#define OFF_ELIST  ((size_t)35205120)     // u32 elist[3][NNODE][64]   1,572,864
#define OFF_NORM   ((size_t)36777984)     // f32 norm[3][NEDGE]          393,216
#define OFF_R1     ((size_t)37171200)     // f32 r1[3][NNODE]             24,576
#define OFF_R2     ((size_t)37195776)     // f32 r2[3][NNODE]             24,576
#define OFF_MP     ((size_t)37220352)     // f32 meanpart[8][64][CH]     524,288

__device__ __forceinline__ void async_lds16(const void* g, void* l) {
  __builtin_amdgcn_global_load_lds((const __attribute__((address_space(1))) void*)g,
                                   (__attribute__((address_space(3))) void*)l, 16, 0, 0);
}

// ---- init: blocks [0,1024) transpose x -> Acat0 f16 + LN0 stats;
//      [1024,1048) zero deg/cnt/r1; [1048,1240) weight fold+transpose tiles ----
__global__ __launch_bounds__(256) void k_init(const float* __restrict__ x,
                                              _Float16* __restrict__ Acat,
                                              float2* __restrict__ part,
                                              const float* __restrict__ cheb_w,
                                              const float* __restrict__ mlp_w,
                                              _Float16* __restrict__ Wt,
                                              _Float16* __restrict__ Mt,
                                              float* __restrict__ deg,
                                              unsigned int* __restrict__ count,
                                              float* __restrict__ r1) {
  __shared__ float rs[512];
  __shared__ _Float16 lt[64][72];
  const int blk = blockIdx.x, t = threadIdx.x;
  if (blk < 1024) {
    int tid = blk*256 + t;
    float s = 0.f, s2 = 0.f;
    for (int i = tid; i < NTOT/4; i += 1024*256) {
      int c4 = i & 63, b = (i >> 6) & 7, n = i >> 9;
      float4 v = ((const float4*)x)[((b*NNODE + n) << 6) + c4];
      half4 o; o[0]=(_Float16)v.x; o[1]=(_Float16)v.y; o[2]=(_Float16)v.z; o[3]=(_Float16)v.w;
      *(half4*)&Acat[(size_t)(i >> 6)*KCAT + c4*4] = o;
      s  += v.x + v.y + v.z + v.w;
      s2 += v.x*v.x + v.y*v.y + v.z*v.z + v.w*v.w;
    }
    rs[t] = s; rs[256+t] = s2; __syncthreads();
    for (int o = 128; o > 0; o >>= 1) {
      if (t < o) { rs[t] += rs[t+o]; rs[256+t] += rs[256+t+o]; }
      __syncthreads();
    }
    if (t == 0) part[blk] = make_float2(rs[0], rs[256]);
  } else if (blk < 1048) {
    int i = (blk - 1024)*256 + t;
    if (i < NLAYER*NNODE) { deg[i] = 0.f; count[i] = 0u; r1[i] = 0.f; }
  } else {
    const int tile = blk - 1048;
    const int rr = t >> 4, c4 = t & 15;
    if (tile < 144) {
      const int l = tile / 48, rem = tile % 48;
      const int kk = rem / 16, q = rem % 16, ci = q >> 2, ni = q & 3;
      const float4* W  = (const float4*)cheb_w + ((size_t)((l*3 + kk)*CH + ci*64))*64 + ni*16;
      const float4* W2 = (const float4*)cheb_w + ((size_t)((l*3 + 2 )*CH + ci*64))*64 + ni*16;
      #pragma unroll
      for (int p = 0; p < 4; ++p) {
        const int r = p*16 + rr;
        float4 v = W[(size_t)r*64 + c4];
        if (kk == 0) {
          float4 v2 = W2[(size_t)r*64 + c4];
          v.x -= v2.x; v.y -= v2.y; v.z -= v2.z; v.w -= v2.w;
        } else if (kk == 2) {
          v.x *= 2.f; v.y *= 2.f; v.z *= 2.f; v.w *= 2.f;
        }
        lt[c4*4+0][r] = (_Float16)v.x; lt[c4*4+1][r] = (_Float16)v.y;
        lt[c4*4+2][r] = (_Float16)v.z; lt[c4*4+3][r] = (_Float16)v.w;
      }
      __syncthreads();
      const int nr = t >> 2, ch2 = t & 3;
      #pragma unroll
      for (int pp = 0; pp < 2; ++pp) {
        const int ch = ch2 + pp*4;
        half8 v = *(const half8*)&lt[nr][ch*8];
        *(half8*)&Wt[((size_t)(l*CH + ni*64 + nr))*KCAT + kk*256 + ci*64 + ch*8] = v;
      }
    } else {
      const int m = tile - 144;
      const int l = m / 16, q = m % 16, ci = q >> 2, ni = q & 3;
      const float4* W = (const float4*)mlp_w + ((size_t)(l*CH + ci*64))*64 + ni*16;
      #pragma unroll
      for (int p = 0; p < 4; ++p) {
        const int r = p*16 + rr;
        float4 v = W[(size_t)r*64 + c4];
        lt[c4*4+0][r] = (_Float16)v.x; lt[c4*4+1][r] = (_Float16)v.y;
        lt[c4*4+2][r] = (_Float16)v.z; lt[c4*4+3][r] = (_Float16)v.w;
      }
      __syncthreads();
      const int nr = t >> 2, ch2 = t & 3;
      #pragma unroll
      for (int pp = 0; pp < 2; ++pp) {
        const int ch = ch2 + pp*4;
        half8 v = *(const half8*)&lt[nr][ch*8];
        *(half8*)&Mt[((size_t)(l*CH + ni*64 + nr))*CH + ci*64 + ch*8] = v;
      }
    }
  }
}

__global__ __launch_bounds__(256) void k_edge_scatter(const int* __restrict__ ei,
                                                      const float* __restrict__ ew,
                                                      float* deg, unsigned int* count,
                                                      unsigned int* elist) {
  int i = blockIdx.x*256 + threadIdx.x;
  if (i >= NLAYER*NEDGE) return;
  int l = i / NEDGE, e = i % NEDGE;
  const int* rows = ei + l*2*NEDGE;
  const int* cols = rows + NEDGE;
  int r = rows[e], c = cols[e];
  float w = (r == c) ? 0.f : ew[i];
  atomicAdd(&deg[l*NNODE + r], w);
  unsigned int slot = atomicAdd(&count[l*NNODE + c], 1u);
  if (slot < 64u) elist[(size_t)(l*NNODE + c)*64 + slot] = (unsigned int)e;
}

__global__ __launch_bounds__(256) void k_edge_norm(const int* __restrict__ ei,
                                                   const float* __restrict__ ew,
                                                   const float* __restrict__ deg,
                                                   float* __restrict__ norm,
                                                   float* __restrict__ r1) {
  int i = blockIdx.x*256 + threadIdx.x;
  if (i >= NLAYER*NEDGE) return;
  int l = i / NEDGE, e = i % NEDGE;
  const int* rows = ei + l*2*NEDGE;
  const int* cols = rows + NEDGE;
  int r = rows[e], c = cols[e];
  float w = (r == c) ? 0.f : ew[i];
  float dr = deg[l*NNODE + r], dc = deg[l*NNODE + c];
  float ir = dr > 0.f ? rsqrtf(fmaxf(dr, 1e-12f)) : 0.f;
  float ic = dc > 0.f ? rsqrtf(fmaxf(dc, 1e-12f)) : 0.f;
  float nm = -(ir * w * ic);
  norm[i] = nm;
  atomicAdd(&r1[l*NNODE + c], nm);
}

// ---- aux: r2 = prop(r1) (blocks 0..23) | cs from Wt (24..32) | csM from Mt (33..35) ----
__global__ __launch_bounds__(256) void k_aux(const int* __restrict__ ei,
                                             const float* __restrict__ norm,
                                             const unsigned int* __restrict__ count,
                                             const unsigned int* __restrict__ elist,
                                             const float* __restrict__ r1,
                                             float* __restrict__ r2,
                                             const _Float16* __restrict__ Wt,
                                             const _Float16* __restrict__ Mt,
                                             float* __restrict__ cs,
                                             float* __restrict__ csM) {
  const int blk = blockIdx.x;
  if (blk < 24) {
    int i = blk*256 + threadIdx.x;
    int l = i / NNODE;
    const int* rows = ei + l*2*NEDGE;
    unsigned int c = count[i]; if (c > 64u) c = 64u;
    const unsigned int* el = elist + (size_t)i*64;
    float s = 0.f;
    for (unsigned int j = 0; j < c; ++j) {
      unsigned int e = el[j];
      s += norm[l*NEDGE + e] * r1[l*NNODE + rows[e]];
    }
    r2[i] = s;
  } else if (blk < 33) {
    int idx = blk - 24;
    int l = idx / 3, kk = idx % 3, n = threadIdx.x;
    const half8* row = (const half8*)&Wt[((size_t)(l*CH + n))*KCAT + kk*256];
    float s = 0.f;
    #pragma unroll 4
    for (int j = 0; j < 32; ++j) {
      half8 v = row[j];
      s += (float)v[0]+(float)v[1]+(float)v[2]+(float)v[3]
         + (float)v[4]+(float)v[5]+(float)v[6]+(float)v[7];
    }
    cs[(l*3 + kk)*CH + n] = s;
  } else {
    int l = blk - 33, n = threadIdx.x;
    const half8* row = (const half8*)&Mt[((size_t)(l*CH + n))*CH];
    float s = 0.f;
    #pragma unroll 4
    for (int j = 0; j < 32; ++j) {
      half8 v = row[j];
      s += (float)v[0]+(float)v[1]+(float)v[2]+(float)v[3]
         + (float)v[4]+(float)v[5]+(float)v[6]+(float)v[7];
    }
    csM[l*CH + n] = s;
  }
}

// ---- sparse prop: one wave per (dst, 4 batches); metadata loaded once per wave;
//      grid 1024 x 256 (4 waves/block) covers 4096 wave-jobs exactly ----
template<int SRC_OFF, int DST_OFF>
__global__ __launch_bounds__(256) void k_prop(_Float16* __restrict__ Acat,
                                              const int* __restrict__ rows,
                                              const float* __restrict__ nrm,
                                              const unsigned int* __restrict__ count,
                                              const unsigned int* __restrict__ el) {
  const int g = blockIdx.x*4 + (threadIdx.x >> 6);   // 0..4095
  const int lane = threadIdx.x & 63;
  const int dst = g >> 1, bb = (g & 1) << 2;         // 4 batches per wave
  unsigned int c = count[dst]; if (c > 64u) c = 64u;
  int srcv = 0; float nmv = 0.f;
  if (lane < (int)c) {
    unsigned int e = el[(size_t)dst*64 + lane];
    srcv = rows[e]; nmv = nrm[e];
  }
  float acc[4][4] = {{0.f,0.f,0.f,0.f},{0.f,0.f,0.f,0.f},{0.f,0.f,0.f,0.f},{0.f,0.f,0.f,0.f}};
  const _Float16* base = Acat + SRC_OFF + lane*4;
  for (unsigned int i = 0; i < c; ++i) {
    int   src = __builtin_amdgcn_readlane(srcv, i);
    int   nbi = __builtin_amdgcn_readlane(__builtin_bit_cast(int, nmv), i);
    float nm  = __builtin_bit_cast(float, nbi);
    const _Float16* p = base + (size_t)(src*8 + bb)*KCAT;
    #pragma unroll
    for (int j = 0; j < 4; ++j) {
      half4 v = *(const half4*)(p + (size_t)j*KCAT);
      acc[j][0] += nm*(float)v[0]; acc[j][1] += nm*(float)v[1];
      acc[j][2] += nm*(float)v[2]; acc[j][3] += nm*(float)v[3];
    }
  }
  #pragma unroll
  for (int j = 0; j < 4; ++j) {
    half4 o; o[0]=(_Float16)acc[j][0]; o[1]=(_Float16)acc[j][1];
    o[2]=(_Float16)acc[j][2]; o[3]=(_Float16)acc[j][3];
    *(half4*)&Acat[(size_t)(dst*8 + bb + j)*KCAT + DST_OFF + lane*4] = o;
  }
}

// ---- MFMA GEMM 64x64 tile, BK=64, XOR-swizzled LDS, LN folded into epilogue.
//      f16-only state: residual read from R (f16), result written to O (f16). ----
template<int KSTEPS, int DO_GELU>
__global__ __launch_bounds__(256) void k_gemm(const _Float16* __restrict__ A, int lda,
                                              const _Float16* __restrict__ Bt, int ldb,
                                              const float* __restrict__ bias,
                                              const float* __restrict__ cs,
                                              const float* __restrict__ r1,
                                              const float* __restrict__ r2,
                                              const float2* __restrict__ part_in,
                                              float2* __restrict__ part_out,
                                              const _Float16* __restrict__ R, int ldr,
                                              _Float16* __restrict__ O, int ldo) {
  __shared__ _Float16 Als[64*64];   // 8 KB
  __shared__ _Float16 Bls[64*64];   // 8 KB
  __shared__ float red[512];
  __shared__ float mv[2];
  const int bm = blockIdx.x, bn = blockIdx.y;
  const int t = threadIdx.x;
  const int w = t >> 6, lane = t & 63;
  const int quad = lane >> 4, l16 = lane & 15;
  const int wm = w & 1, wn = w >> 1;   // wave tile: 32x32

  // ---- reduce stats partials of input h -> (mean, istd) ----
  {
    float s = 0.f, s2 = 0.f;
    for (int i = t; i < 1024; i += 256) { float2 p = part_in[i]; s += p.x; s2 += p.y; }
    red[t] = s; red[256+t] = s2; __syncthreads();
    for (int o = 128; o > 0; o >>= 1) {
      if (t < o) { red[t] += red[t+o]; red[256+t] += red[256+t+o]; }
      __syncthreads();
    }
    if (t == 0) {
      float mean = red[0] * (1.f/(float)NTOT);
      float var  = red[256] * (1.f/(float)NTOT) - mean*mean;
      mv[0] = mean; mv[1] = rsqrtf(var + 1e-5f);
    }
    __syncthreads();
  }
  const float mean = mv[0], istd = mv[1];

  f32x4 acc00 = {0.f,0.f,0.f,0.f};
  f32x4 acc01 = acc00, acc10 = acc00, acc11 = acc00;

  // staging: XOR-swizzled by row so LDS seg s holds global kseg s^(row&7)
  const int c0 = w*64 + lane, c1 = 256 + w*64 + lane;
  const int r0 = c0 >> 3, s0 = (c0 & 7) ^ (r0 & 7);
  const int r1i = c1 >> 3, s1 = (c1 & 7) ^ (r1i & 7);
  const _Float16* ga0 = A  + (size_t)(bm*64 + r0)*lda + s0*8;
  const _Float16* ga1 = A  + (size_t)(bm*64 + r1i)*lda + s1*8;
  const _Float16* gb0 = Bt + (size_t)(bn*64 + r0)*ldb + s0*8;
  const _Float16* gb1 = Bt + (size_t)(bn*64 + r1i)*ldb + s1*8;
  _Float16* lA0 = &Als[w*512];        // wave-uniform bases; HW scatters lane*16B
  _Float16* lA1 = &Als[2048 + w*512];
  _Float16* lB0 = &Bls[w*512];
  _Float16* lB1 = &Bls[2048 + w*512];

  const int ra0 = wm*32 + l16, ra1 = ra0 + 16;
  const int rb0 = wn*32 + l16, rb1 = rb0 + 16;

  for (int ks = 0; ks < KSTEPS; ++ks) {
    async_lds16(ga0, lA0); async_lds16(ga1, lA1);
    async_lds16(gb0, lB0); async_lds16(gb1, lB1);
    ga0 += 64; ga1 += 64; gb0 += 64; gb1 += 64;
    __syncthreads();
    #pragma unroll
    for (int kh = 0; kh < 2; ++kh) {   // k-half: global kseg = kh*4 + quad
      const int q = kh*4 + quad;
      half8 a0 = *(const half8*)&Als[ra0*64 + (q ^ (ra0 & 7))*8];
      half8 a1 = *(const half8*)&Als[ra1*64 + (q ^ (ra1 & 7))*8];
      half8 b0 = *(const half8*)&Bls[rb0*64 + (q ^ (rb0 & 7))*8];
      half8 b1 = *(const half8*)&Bls[rb1*64 + (q ^ (rb1 & 7))*8];
      acc00 = __builtin_amdgcn_mfma_f32_16x16x32_f16(a0, b0, acc00, 0, 0, 0);
      acc01 = __builtin_amdgcn_mfma_f32_16x16x32_f16(a0, b1, acc01, 0, 0, 0);
      acc10 = __builtin_amdgcn_mfma_f32_16x16x32_f16(a1, b0, acc10, 0, 0, 0);
      acc11 = __builtin_amdgcn_mfma_f32_16x16x32_f16(a1, b1, acc11, 0, 0, 0);
    }
    __syncthreads();
  }

  float s = 0.f, s2 = 0.f;
  const int gm0 = bm*64 + wm*32, gn0 = bn*64 + wn*32;
  const float mi = -mean * istd;
  #pragma unroll
  for (int i = 0; i < 2; ++i) {
    #pragma unroll
    for (int j = 0; j < 2; ++j) {
      f32x4 a = (i == 0) ? (j == 0 ? acc00 : acc01) : (j == 0 ? acc10 : acc11);
      const int col = gn0 + j*16 + l16;
      const float bv = bias[col];
      const float c0v = cs[col];
      float c1v = 0.f, c2v = 0.f;
      if (!DO_GELU) { c1v = cs[256 + col]; c2v = cs[512 + col]; }
      #pragma unroll
      for (int r = 0; r < 4; ++r) {
        const int row = gm0 + i*16 + quad*4 + r;   // C/D: col=lane&15, row=quad*4+reg
        float v;
        if (DO_GELU) {
          v = istd*a[r] + mi*c0v + bv;
          v = 0.5f*v*(1.f + erff(v*0.70710678118654752f));
        } else {
          const int node = row >> 3;
          v = istd*a[r] + mi*(c0v + r1[node]*c1v + r2[node]*c2v) + bv;
        }
        float hv = (float)R[(size_t)row*ldr + col] + v;
        O[(size_t)row*ldo + col] = (_Float16)hv;
        s += hv; s2 += hv*hv;
      }
    }
  }
  red[t] = s; red[256+t] = s2; __syncthreads();
  for (int o = 128; o > 0; o >>= 1) {
    if (t < o) { red[t] += red[t+o]; red[256+t] += red[256+t+o]; }
    __syncthreads();
  }
  if (t == 0) part_out[blockIdx.y*gridDim.x + blockIdx.x] = make_float2(red[0], red[256]);
}

// ---- final mean over N (reads f16 h in Acat[:,0:256)) ----
__global__ __launch_bounds__(256) void k_mean_part(const _Float16* __restrict__ Acat,
                                                   float* __restrict__ mp) {
  int blk = blockIdx.x;          // 512 blocks: b = blk&7, chunk = blk>>3 (32 n's each)
  int b = blk & 7, chunk = blk >> 3;
  int c = threadIdx.x;
  float s = 0.f;
  for (int k = 0; k < 32; ++k) {
    int n = chunk*32 + k;
    s += (float)Acat[(size_t)(n*8 + b)*KCAT + c];
  }
  mp[((b*64 + chunk) << 8) + c] = s;
}

__global__ __launch_bounds__(256) void k_mean_final(const float* __restrict__ mp,
                                                    float* __restrict__ out) {
  int b = blockIdx.x, c = threadIdx.x;
  float s = 0.f;
  for (int ch = 0; ch < 64; ++ch) s += mp[((b*64 + ch) << 8) + c];
  out[(b << 8) + c] = s * (1.f/(float)NNODE);
}

extern "C" void kernel_launch(void* const* d_in, const int* in_sizes, int n_in,
                              void* d_out, int out_size, void* d_ws, size_t ws_size,
                              hipStream_t stream) {
  const float* x      = (const float*)d_in[0];   // node_feature [8,2048,256]
  const float* ew     = (const float*)d_in[1];   // edge_weight [3,32768]
  const float* cheb_w = (const float*)d_in[2];   // [3,3,256,256]
  const float* cheb_b = (const float*)d_in[3];   // [3,256]
  const float* mlp_w  = (const float*)d_in[4];   // [3,256,256]
  const float* mlp_b  = (const float*)d_in[5];   // [3,256]
  const int*   ei     = (const int*)d_in[6];     // [3,2,32768]
  float* out = (float*)d_out;

  char* ws = (char*)d_ws;
  _Float16*     Acat  = (_Float16*)(ws + OFF_ACAT);
  _Float16*     Hf    = (_Float16*)(ws + OFF_HF);
  _Float16*     Wt    = (_Float16*)(ws + OFF_WT);
  _Float16*     Mt    = (_Float16*)(ws + OFF_MT);
  float2*       partA = (float2*)(ws + OFF_PARTA);
  float2*       partB = (float2*)(ws + OFF_PARTB);
  float*        cs    = (float*)(ws + OFF_CS);
  float*        csM   = (float*)(ws + OFF_CSM);
  float*        deg   = (float*)(ws + OFF_DEG);
  unsigned int* cnt   = (unsigned int*)(ws + OFF_CNT);
  unsigned int* elist = (unsigned int*)(ws + OFF_ELIST);
  float*        norm  = (float*)(ws + OFF_NORM);
  float*        r1    = (float*)(ws + OFF_R1);
  float*        r2    = (float*)(ws + OFF_R2);
  float*        mp    = (float*)(ws + OFF_MP);

  k_init<<<1240, 256, 0, stream>>>(x, Acat, partA, cheb_w, mlp_w, Wt, Mt, deg, cnt, r1);
  k_edge_scatter<<<(NLAYER*NEDGE)/256, 256, 0, stream>>>(ei, ew, deg, cnt, elist);
  k_edge_norm<<<(NLAYER*NEDGE)/256, 256, 0, stream>>>(ei, ew, deg, norm, r1);
  k_aux<<<36, 256, 0, stream>>>(ei, norm, cnt, elist, r1, r2, Wt, Mt, cs, csM);

  for (int l = 0; l < NLAYER; ++l) {
    const int* rows_l = ei + l*2*NEDGE;
    const unsigned int* cnt_l = cnt + l*NNODE;
    const unsigned int* el_l  = elist + (size_t)l*NNODE*64;
    const float* norm_l = norm + l*NEDGE;

    // P1 = prop(h) -> Acat[:,256:512)
    k_prop<0, 256><<<1024, 256, 0, stream>>>(Acat, rows_l, norm_l, cnt_l, el_l);
    // P2 = prop(P1) -> Acat[:,512:768)
    k_prop<256, 512><<<1024, 256, 0, stream>>>(Acat, rows_l, norm_l, cnt_l, el_l);
    // Hf = h + LN-corrected [h|P1|P2]@W' + cheb_b ; stats -> partB
    k_gemm<12, 0><<<dim3(256, 4), 256, 0, stream>>>(
        Acat, KCAT, Wt + (size_t)l*CH*KCAT, KCAT, cheb_b + l*CH,
        cs + l*3*CH, r1 + l*NNODE, r2 + l*NNODE, partA, partB,
        Acat, KCAT, Hf, CH);
    // h(new, ->Acat0) = Hf + gelu(LN-corrected Hf@M + mlp_b) ; stats -> partA
    k_gemm<4, 1><<<dim3(256, 4), 256, 0, stream>>>(
        Hf, CH, Mt + (size_t)l*CH*CH, CH, mlp_b + l*CH,
        csM + l*CH, r1, r2, partB, partA,
        Hf, CH, Acat, KCAT);
  }

  k_mean_part<<<512, 256, 0, stream>>>(Acat, mp);
  k_mean_final<<<8, 256, 0, stream>>>(mp, out);
}

// Round 9
// 299.210 us; speedup vs baseline: 3.4173x; 1.0527x over previous
//
#include <hip/hip_runtime.h>

#define BATCH   8
#define NNODE   2048
#define CH      256
#define NEDGE   32768
#define NLAYER  3
#define MROWS   (NNODE*BATCH)      // 16384 rows (n-major: row = n*8 + b)
#define KCAT    (3*CH)             // 768
#define NTOT    (MROWS*CH)         // 4,194,304 elements of h

typedef _Float16 half8 __attribute__((ext_vector_type(8)));
typedef _Float16 half4 __attribute__((ext_vector_type(4)));
typedef float    f32x4 __attribute__((ext_vector_type(4)));

// ---------------- workspace layout (bytes) ----------------
// h lives ONLY in f16: Acat[:,0:256) is the current h; Hf is the mid-layer h.
// Acat cols: [0:256)=h f16, [256:512)=P1=prop(h), [512:768)=P2=prop(P1)
#define OFF_ACAT   ((size_t)0)            // f16 [MROWS][768]         25,165,824
#define OFF_HF     ((size_t)25165824)     // f16 Hf [MROWS][256]       8,388,608
#define OFF_WT     ((size_t)33554432)     // f16 Wt [3][CH][KCAT]      1,179,648
#define OFF_MT     ((size_t)34734080)     // f16 Mt [3][CH][CH]          393,216
#define OFF_PARTA  ((size_t)35127296)     // float2[1024]                  8,192
#define OFF_PARTB  ((size_t)35135488)     // float2[1024]                  8,192
#define OFF_CS     ((size_t)35143680)     // f32 cs[3][3][256]             9,216
#define OFF_CSM    ((size_t)35152896)     // f32 csM[3][256]               3,072
#define OFF_DEG    ((size_t)35155968)     // f32 deg[3][NNODE]            24,576
#define OFF_CNT    ((size_t)35180544)     // u32 count[3][NNODE]          24,576
#define OFF_ELIST  ((size_t)35205120)     // u32 elist[3][NNODE][64]   1,572,864
#define OFF_NORM   ((size_t)36777984)     // f32 norm[3][NEDGE]           393,216
#define OFF_R1     ((size_t)37171200)     // f32 r1[3][NNODE]             24,576
#define OFF_R2     ((size_t)37195776)     // f32 r2[3][NNODE]             24,576

__device__ __forceinline__ void async_lds16(const void* g, void* l) {
  __builtin_amdgcn_global_load_lds((const __attribute__((address_space(1))) void*)g,
                                   (__attribute__((address_space(3))) void*)l, 16, 0, 0);
}

// ---- init: blocks [0,1024) transpose x -> Acat0 f16 + LN0 stats;
//      [1024,1048) zero deg/cnt/r1; [1048,1240) weight fold+transpose tiles ----
__global__ __launch_bounds__(256) void k_init(const float* __restrict__ x,
                                              _Float16* __restrict__ Acat,
                                              float2* __restrict__ part,
                                              const float* __restrict__ cheb_w,
                                              const float* __restrict__ mlp_w,
                                              _Float16* __restrict__ Wt,
                                              _Float16* __restrict__ Mt,
                                              float* __restrict__ deg,
                                              unsigned int* __restrict__ count,
                                              float* __restrict__ r1) {
  __shared__ float rs[512];
  __shared__ _Float16 lt[64][72];
  const int blk = blockIdx.x, t = threadIdx.x;
  if (blk < 1024) {
    int tid = blk*256 + t;
    float s = 0.f, s2 = 0.f;
    for (int i = tid; i < NTOT/4; i += 1024*256) {
      int c4 = i & 63, b = (i >> 6) & 7, n = i >> 9;
      float4 v = ((const float4*)x)[((b*NNODE + n) << 6) + c4];
      half4 o; o[0]=(_Float16)v.x; o[1]=(_Float16)v.y; o[2]=(_Float16)v.z; o[3]=(_Float16)v.w;
      *(half4*)&Acat[(size_t)(i >> 6)*KCAT + c4*4] = o;
      s  += v.x + v.y + v.z + v.w;
      s2 += v.x*v.x + v.y*v.y + v.z*v.z + v.w*v.w;
    }
    rs[t] = s; rs[256+t] = s2; __syncthreads();
    for (int o = 128; o > 0; o >>= 1) {
      if (t < o) { rs[t] += rs[t+o]; rs[256+t] += rs[256+t+o]; }
      __syncthreads();
    }
    if (t == 0) part[blk] = make_float2(rs[0], rs[256]);
  } else if (blk < 1048) {
    int i = (blk - 1024)*256 + t;
    if (i < NLAYER*NNODE) { deg[i] = 0.f; count[i] = 0u; r1[i] = 0.f; }
  } else {
    const int tile = blk - 1048;
    const int rr = t >> 4, c4 = t & 15;
    if (tile < 144) {
      const int l = tile / 48, rem = tile % 48;
      const int kk = rem / 16, q = rem % 16, ci = q >> 2, ni = q & 3;
      const float4* W  = (const float4*)cheb_w + ((size_t)((l*3 + kk)*CH + ci*64))*64 + ni*16;
      const float4* W2 = (const float4*)cheb_w + ((size_t)((l*3 + 2 )*CH + ci*64))*64 + ni*16;
      #pragma unroll
      for (int p = 0; p < 4; ++p) {
        const int r = p*16 + rr;
        float4 v = W[(size_t)r*64 + c4];
        if (kk == 0) {
          float4 v2 = W2[(size_t)r*64 + c4];
          v.x -= v2.x; v.y -= v2.y; v.z -= v2.z; v.w -= v2.w;
        } else if (kk == 2) {
          v.x *= 2.f; v.y *= 2.f; v.z *= 2.f; v.w *= 2.f;
        }
        lt[c4*4+0][r] = (_Float16)v.x; lt[c4*4+1][r] = (_Float16)v.y;
        lt[c4*4+2][r] = (_Float16)v.z; lt[c4*4+3][r] = (_Float16)v.w;
      }
      __syncthreads();
      const int nr = t >> 2, ch2 = t & 3;
      #pragma unroll
      for (int pp = 0; pp < 2; ++pp) {
        const int ch = ch2 + pp*4;
        half8 v = *(const half8*)&lt[nr][ch*8];
        *(half8*)&Wt[((size_t)(l*CH + ni*64 + nr))*KCAT + kk*256 + ci*64 + ch*8] = v;
      }
    } else {
      const int m = tile - 144;
      const int l = m / 16, q = m % 16, ci = q >> 2, ni = q & 3;
      const float4* W = (const float4*)mlp_w + ((size_t)(l*CH + ci*64))*64 + ni*16;
      #pragma unroll
      for (int p = 0; p < 4; ++p) {
        const int r = p*16 + rr;
        float4 v = W[(size_t)r*64 + c4];
        lt[c4*4+0][r] = (_Float16)v.x; lt[c4*4+1][r] = (_Float16)v.y;
        lt[c4*4+2][r] = (_Float16)v.z; lt[c4*4+3][r] = (_Float16)v.w;
      }
      __syncthreads();
      const int nr = t >> 2, ch2 = t & 3;
      #pragma unroll
      for (int pp = 0; pp < 2; ++pp) {
        const int ch = ch2 + pp*4;
        half8 v = *(const half8*)&lt[nr][ch*8];
        *(half8*)&Mt[((size_t)(l*CH + ni*64 + nr))*CH + ci*64 + ch*8] = v;
      }
    }
  }
}

__global__ __launch_bounds__(256) void k_edge_scatter(const int* __restrict__ ei,
                                                      const float* __restrict__ ew,
                                                      float* deg, unsigned int* count,
                                                      unsigned int* elist) {
  int i = blockIdx.x*256 + threadIdx.x;
  if (i >= NLAYER*NEDGE) return;
  int l = i / NEDGE, e = i % NEDGE;
  const int* rows = ei + l*2*NEDGE;
  const int* cols = rows + NEDGE;
  int r = rows[e], c = cols[e];
  float w = (r == c) ? 0.f : ew[i];
  atomicAdd(&deg[l*NNODE + r], w);
  unsigned int slot = atomicAdd(&count[l*NNODE + c], 1u);
  if (slot < 64u) elist[(size_t)(l*NNODE + c)*64 + slot] = (unsigned int)e;
}

__global__ __launch_bounds__(256) void k_edge_norm(const int* __restrict__ ei,
                                                   const float* __restrict__ ew,
                                                   const float* __restrict__ deg,
                                                   float* __restrict__ norm,
                                                   float* __restrict__ r1) {
  int i = blockIdx.x*256 + threadIdx.x;
  if (i >= NLAYER*NEDGE) return;
  int l = i / NEDGE, e = i % NEDGE;
  const int* rows = ei + l*2*NEDGE;
  const int* cols = rows + NEDGE;
  int r = rows[e], c = cols[e];
  float w = (r == c) ? 0.f : ew[i];
  float dr = deg[l*NNODE + r], dc = deg[l*NNODE + c];
  float ir = dr > 0.f ? rsqrtf(fmaxf(dr, 1e-12f)) : 0.f;
  float ic = dc > 0.f ? rsqrtf(fmaxf(dc, 1e-12f)) : 0.f;
  float nm = -(ir * w * ic);
  norm[i] = nm;
  atomicAdd(&r1[l*NNODE + c], nm);
}

// ---- sparse prop: wave = one (dst,b); b = blk&7 pins each batch slice (1 MB)
//      to one XCD's L2. 4 waves/block, 4 consecutive dsts. Blocks >= 4096 (AUX
//      instantiation only, first launch of layer 0) do r2/cs/csM/out-zero. ----
template<int SRC_OFF, int DST_OFF, int AUX>
__global__ __launch_bounds__(256) void k_prop(_Float16* __restrict__ Acat,
                                              const int* __restrict__ rows,
                                              const float* __restrict__ nrm,
                                              const unsigned int* __restrict__ count,
                                              const unsigned int* __restrict__ el,
                                              const int* __restrict__ ei,
                                              const float* __restrict__ norm_all,
                                              const unsigned int* __restrict__ cnt_all,
                                              const unsigned int* __restrict__ el_all,
                                              const float* __restrict__ r1,
                                              float* __restrict__ r2,
                                              const _Float16* __restrict__ Wt,
                                              const _Float16* __restrict__ Mt,
                                              float* __restrict__ cs,
                                              float* __restrict__ csM,
                                              float* __restrict__ out_zero) {
  const int blk = blockIdx.x, t = threadIdx.x;
  if (!AUX || blk < 4096) {
    const int b = blk & 7, dgrp = blk >> 3;
    const int w = t >> 6, lane = t & 63;
    const int dst = dgrp*4 + w;
    unsigned int c = count[dst]; if (c > 64u) c = 64u;
    int srcv = 0; float nmv = 0.f;
    if (lane < (int)c) {
      unsigned int e = el[(size_t)dst*64 + lane];
      srcv = rows[e]; nmv = nrm[e];
    }
    float a0 = 0.f, a1 = 0.f, a2 = 0.f, a3 = 0.f;
    const _Float16* base = Acat + SRC_OFF + b*KCAT + lane*4;
    #define PROP_STEP(i)                                                            \
      {                                                                             \
        int   src = __builtin_amdgcn_readlane(srcv, (i));                           \
        int   nbi = __builtin_amdgcn_readlane(__builtin_bit_cast(int, nmv), (i));   \
        float nm  = __builtin_bit_cast(float, nbi);                                 \
        half4 v = *(const half4*)&base[(size_t)src*8*KCAT];                         \
        a0 += nm*(float)v[0]; a1 += nm*(float)v[1];                                 \
        a2 += nm*(float)v[2]; a3 += nm*(float)v[3];                                 \
      }
    unsigned int i = 0;
    for (; i + 4 <= c; i += 4) { PROP_STEP(i) PROP_STEP(i+1) PROP_STEP(i+2) PROP_STEP(i+3) }
    for (; i < c; ++i) { PROP_STEP(i) }
    #undef PROP_STEP
    half4 o; o[0] = (_Float16)a0; o[1] = (_Float16)a1; o[2] = (_Float16)a2; o[3] = (_Float16)a3;
    *(half4*)&Acat[(size_t)(dst*8 + b)*KCAT + DST_OFF + lane*4] = o;
  } else {
    const int tile = blk - 4096;
    if (tile < 24) {
      int i = tile*256 + t, l = i / NNODE;
      const int* rw = ei + l*2*NEDGE;
      unsigned int c = cnt_all[i]; if (c > 64u) c = 64u;
      const unsigned int* elp = el_all + (size_t)i*64;
      float s = 0.f;
      for (unsigned int j = 0; j < c; ++j) {
        unsigned int e = elp[j];
        s += norm_all[l*NEDGE + e] * r1[l*NNODE + rw[e]];
      }
      r2[i] = s;
    } else if (tile < 33) {
      int idx = tile - 24, l = idx / 3, kk = idx % 3, n = t;
      const half8* row = (const half8*)&Wt[((size_t)(l*CH + n))*KCAT + kk*256];
      float s = 0.f;
      #pragma unroll 4
      for (int j = 0; j < 32; ++j) {
        half8 v = row[j];
        s += (float)v[0]+(float)v[1]+(float)v[2]+(float)v[3]
           + (float)v[4]+(float)v[5]+(float)v[6]+(float)v[7];
      }
      cs[(l*3 + kk)*CH + n] = s;
    } else if (tile < 36) {
      int l = tile - 33, n = t;
      const half8* row = (const half8*)&Mt[((size_t)(l*CH + n))*CH];
      float s = 0.f;
      #pragma unroll 4
      for (int j = 0; j < 32; ++j) {
        half8 v = row[j];
        s += (float)v[0]+(float)v[1]+(float)v[2]+(float)v[3]
           + (float)v[4]+(float)v[5]+(float)v[6]+(float)v[7];
      }
      csM[l*CH + n] = s;
    } else {
      for (int i = t; i < BATCH*CH; i += 256) out_zero[i] = 0.f;
    }
  }
}

// ---- MFMA GEMM 64x64 tile, BK=64, XOR-swizzled LDS, LN folded into epilogue.
//      f16-only state: residual read from R (f16), result written to O (f16). ----
template<int KSTEPS, int DO_GELU>
__global__ __launch_bounds__(256) void k_gemm(const _Float16* __restrict__ A, int lda,
                                              const _Float16* __restrict__ Bt, int ldb,
                                              const float* __restrict__ bias,
                                              const float* __restrict__ cs,
                                              const float* __restrict__ r1,
                                              const float* __restrict__ r2,
                                              const float2* __restrict__ part_in,
                                              float2* __restrict__ part_out,
                                              const _Float16* __restrict__ R, int ldr,
                                              _Float16* __restrict__ O, int ldo) {
  __shared__ _Float16 Als[64*64];   // 8 KB
  __shared__ _Float16 Bls[64*64];   // 8 KB
  __shared__ float red[512];
  __shared__ float mv[2];
  const int bm = blockIdx.x, bn = blockIdx.y;
  const int t = threadIdx.x;
  const int w = t >> 6, lane = t & 63;
  const int quad = lane >> 4, l16 = lane & 15;
  const int wm = w & 1, wn = w >> 1;   // wave tile: 32x32

  // ---- reduce stats partials of input h -> (mean, istd) ----
  {
    float s = 0.f, s2 = 0.f;
    for (int i = t; i < 1024; i += 256) { float2 p = part_in[i]; s += p.x; s2 += p.y; }
    red[t] = s; red[256+t] = s2; __syncthreads();
    for (int o = 128; o > 0; o >>= 1) {
      if (t < o) { red[t] += red[t+o]; red[256+t] += red[256+t+o]; }
      __syncthreads();
    }
    if (t == 0) {
      float mean = red[0] * (1.f/(float)NTOT);
      float var  = red[256] * (1.f/(float)NTOT) - mean*mean;
      mv[0] = mean; mv[1] = rsqrtf(var + 1e-5f);
    }
    __syncthreads();
  }
  const float mean = mv[0], istd = mv[1];

  f32x4 acc00 = {0.f,0.f,0.f,0.f};
  f32x4 acc01 = acc00, acc10 = acc00, acc11 = acc00;

  // staging: XOR-swizzled by row so LDS seg s holds global kseg s^(row&7)
  const int c0 = w*64 + lane, c1 = 256 + w*64 + lane;
  const int r0 = c0 >> 3, s0 = (c0 & 7) ^ (r0 & 7);
  const int r1i = c1 >> 3, s1 = (c1 & 7) ^ (r1i & 7);
  const _Float16* ga0 = A  + (size_t)(bm*64 + r0)*lda + s0*8;
  const _Float16* ga1 = A  + (size_t)(bm*64 + r1i)*lda + s1*8;
  const _Float16* gb0 = Bt + (size_t)(bn*64 + r0)*ldb + s0*8;
  const _Float16* gb1 = Bt + (size_t)(bn*64 + r1i)*ldb + s1*8;
  _Float16* lA0 = &Als[w*512];        // wave-uniform bases; HW scatters lane*16B
  _Float16* lA1 = &Als[2048 + w*512];
  _Float16* lB0 = &Bls[w*512];
  _Float16* lB1 = &Bls[2048 + w*512];

  const int ra0 = wm*32 + l16, ra1 = ra0 + 16;
  const int rb0 = wn*32 + l16, rb1 = rb0 + 16;

  for (int ks = 0; ks < KSTEPS; ++ks) {
    async_lds16(ga0, lA0); async_lds16(ga1, lA1);
    async_lds16(gb0, lB0); async_lds16(gb1, lB1);
    ga0 += 64; ga1 += 64; gb0 += 64; gb1 += 64;
    __syncthreads();
    #pragma unroll
    for (int kh = 0; kh < 2; ++kh) {   // k-half: global kseg = kh*4 + quad
      const int q = kh*4 + quad;
      half8 a0 = *(const half8*)&Als[ra0*64 + (q ^ (ra0 & 7))*8];
      half8 a1 = *(const half8*)&Als[ra1*64 + (q ^ (ra1 & 7))*8];
      half8 b0 = *(const half8*)&Bls[rb0*64 + (q ^ (rb0 & 7))*8];
      half8 b1 = *(const half8*)&Bls[rb1*64 + (q ^ (rb1 & 7))*8];
      acc00 = __builtin_amdgcn_mfma_f32_16x16x32_f16(a0, b0, acc00, 0, 0, 0);
      acc01 = __builtin_amdgcn_mfma_f32_16x16x32_f16(a0, b1, acc01, 0, 0, 0);
      acc10 = __builtin_amdgcn_mfma_f32_16x16x32_f16(a1, b0, acc10, 0, 0, 0);
      acc11 = __builtin_amdgcn_mfma_f32_16x16x32_f16(a1, b1, acc11, 0, 0, 0);
    }
    __syncthreads();
  }

  float s = 0.f, s2 = 0.f;
  const int gm0 = bm*64 + wm*32, gn0 = bn*64 + wn*32;
  const float mi = -mean * istd;
  #pragma unroll
  for (int i = 0; i < 2; ++i) {
    #pragma unroll
    for (int j = 0; j < 2; ++j) {
      f32x4 a = (i == 0) ? (j == 0 ? acc00 : acc01) : (j == 0 ? acc10 : acc11);
      const int col = gn0 + j*16 + l16;
      const float bv = bias[col];
      const float c0v = cs[col];
      float c1v = 0.f, c2v = 0.f;
      if (!DO_GELU) { c1v = cs[256 + col]; c2v = cs[512 + col]; }
      #pragma unroll
      for (int r = 0; r < 4; ++r) {
        const int row = gm0 + i*16 + quad*4 + r;   // C/D: col=lane&15, row=quad*4+reg
        float v;
        if (DO_GELU) {
          v = istd*a[r] + mi*c0v + bv;
          v = 0.5f*v*(1.f + erff(v*0.70710678118654752f));
        } else {
          const int node = row >> 3;
          v = istd*a[r] + mi*(c0v + r1[node]*c1v + r2[node]*c2v) + bv;
        }
        float hv = (float)R[(size_t)row*ldr + col] + v;
        O[(size_t)row*ldo + col] = (_Float16)hv;
        s += hv; s2 += hv*hv;
      }
    }
  }
  red[t] = s; red[256+t] = s2; __syncthreads();
  for (int o = 128; o > 0; o >>= 1) {
    if (t < o) { red[t] += red[t+o]; red[256+t] += red[256+t+o]; }
    __syncthreads();
  }
  if (t == 0) part_out[blockIdx.y*gridDim.x + blockIdx.x] = make_float2(red[0], red[256]);
}

// ---- final mean over N: 64 blocks, atomicAdd into pre-zeroed out ----
__global__ __launch_bounds__(256) void k_mean(const _Float16* __restrict__ Acat,
                                              float* __restrict__ out) {
  int b = blockIdx.x & 7, chunk = blockIdx.x >> 3;   // 8 chunks x 256 nodes
  int c = threadIdx.x;
  float s = 0.f;
  for (int k = 0; k < 256; ++k) {
    int n = chunk*256 + k;
    s += (float)Acat[(size_t)(n*8 + b)*KCAT + c];
  }
  atomicAdd(&out[(b << 8) + c], s * (1.f/(float)NNODE));
}

extern "C" void kernel_launch(void* const* d_in, const int* in_sizes, int n_in,
                              void* d_out, int out_size, void* d_ws, size_t ws_size,
                              hipStream_t stream) {
  const float* x      = (const float*)d_in[0];   // node_feature [8,2048,256]
  const float* ew     = (const float*)d_in[1];   // edge_weight [3,32768]
  const float* cheb_w = (const float*)d_in[2];   // [3,3,256,256]
  const float* cheb_b = (const float*)d_in[3];   // [3,256]
  const float* mlp_w  = (const float*)d_in[4];   // [3,256,256]
  const float* mlp_b  = (const float*)d_in[5];   // [3,256]
  const int*   ei     = (const int*)d_in[6];     // [3,2,32768]
  float* out = (float*)d_out;

  char* ws = (char*)d_ws;
  _Float16*     Acat  = (_Float16*)(ws + OFF_ACAT);
  _Float16*     Hf    = (_Float16*)(ws + OFF_HF);
  _Float16*     Wt    = (_Float16*)(ws + OFF_WT);
  _Float16*     Mt    = (_Float16*)(ws + OFF_MT);
  float2*       partA = (float2*)(ws + OFF_PARTA);
  float2*       partB = (float2*)(ws + OFF_PARTB);
  float*        cs    = (float*)(ws + OFF_CS);
  float*        csM   = (float*)(ws + OFF_CSM);
  float*        deg   = (float*)(ws + OFF_DEG);
  unsigned int* cnt   = (unsigned int*)(ws + OFF_CNT);
  unsigned int* elist = (unsigned int*)(ws + OFF_ELIST);
  float*        norm  = (float*)(ws + OFF_NORM);
  float*        r1    = (float*)(ws + OFF_R1);
  float*        r2    = (float*)(ws + OFF_R2);

  k_init<<<1240, 256, 0, stream>>>(x, Acat, partA, cheb_w, mlp_w, Wt, Mt, deg, cnt, r1);
  k_edge_scatter<<<(NLAYER*NEDGE)/256, 256, 0, stream>>>(ei, ew, deg, cnt, elist);
  k_edge_norm<<<(NLAYER*NEDGE)/256, 256, 0, stream>>>(ei, ew, deg, norm, r1);

  for (int l = 0; l < NLAYER; ++l) {
    const int* rows_l = ei + l*2*NEDGE;
    const unsigned int* cnt_l = cnt + l*NNODE;
    const unsigned int* el_l  = elist + (size_t)l*NNODE*64;
    const float* norm_l = norm + l*NEDGE;

    // P1 = prop(h) -> Acat[:,256:512). Layer 0 also runs aux blocks (r2/cs/csM/out=0).
    if (l == 0) {
      k_prop<0, 256, 1><<<4133, 256, 0, stream>>>(
          Acat, rows_l, norm_l, cnt_l, el_l,
          ei, norm, cnt, elist, r1, r2, Wt, Mt, cs, csM, out);
    } else {
      k_prop<0, 256, 0><<<4096, 256, 0, stream>>>(
          Acat, rows_l, norm_l, cnt_l, el_l,
          ei, norm, cnt, elist, r1, r2, Wt, Mt, cs, csM, out);
    }
    // P2 = prop(P1) -> Acat[:,512:768)
    k_prop<256, 512, 0><<<4096, 256, 0, stream>>>(
        Acat, rows_l, norm_l, cnt_l, el_l,
        ei, norm, cnt, elist, r1, r2, Wt, Mt, cs, csM, out);
    // Hf = h + LN-corrected [h|P1|P2]@W' + cheb_b ; stats -> partB
    k_gemm<12, 0><<<dim3(256, 4), 256, 0, stream>>>(
        Acat, KCAT, Wt + (size_t)l*CH*KCAT, KCAT, cheb_b + l*CH,
        cs + l*3*CH, r1 + l*NNODE, r2 + l*NNODE, partA, partB,
        Acat, KCAT, Hf, CH);
    // h(new, ->Acat0) = Hf + gelu(LN-corrected Hf@M + mlp_b) ; stats -> partA
    k_gemm<4, 1><<<dim3(256, 4), 256, 0, stream>>>(
        Hf, CH, Mt + (size_t)l*CH*CH, CH, mlp_b + l*CH,
        csM + l*CH, r1, r2, partB, partA,
        Hf, CH, Acat, KCAT);
  }

  k_mean<<<64, 256, 0, stream>>>(Acat, out);
}